// Round 2
// baseline (814.111 us; speedup 1.0000x reference)
//
#include <hip/hip_runtime.h>

#define NN 100000
#define EE 1600000
#define DD 128

static __device__ __forceinline__ float dot4(float4 a, float4 b) {
  return a.x * b.x + a.y * b.y + a.z * b.z + a.w * b.w;
}

// ---- degree counting: per-XCD privatized histograms, L2-local atomics ----
// Copy x of each histogram is updated ONLY by blocks executing on XCD x
// (runtime XCC_ID), with workgroup-scope atomics -> global_atomic_add with no
// sc bits -> executes in the XCD-local TCC (L2), which serializes all requests
// from that XCD. 800KB/XCD stays L2-resident; end-of-kernel release flushes.
__global__ __launch_bounds__(256) void count8_k(const int* __restrict__ src,
                                                const int* __restrict__ dst,
                                                unsigned* __restrict__ cs8,
                                                unsigned* __restrict__ cd8) {
  int i = blockIdx.x * 256 + threadIdx.x;
  unsigned xcd;
  asm volatile("s_getreg_b32 %0, hwreg(HW_REG_XCC_ID)" : "=s"(xcd));
  xcd &= 7u;
  if (i < EE) {
    unsigned s = (unsigned)src[i];
    unsigned d = (unsigned)dst[i];
    __hip_atomic_fetch_add(cs8 + (size_t)xcd * NN + s, 1u, __ATOMIC_RELAXED,
                           __HIP_MEMORY_SCOPE_WORKGROUP);
    __hip_atomic_fetch_add(cd8 + (size_t)xcd * NN + d, 1u, __ATOMIC_RELAXED,
                           __HIP_MEMORY_SCOPE_WORKGROUP);
  }
}

// ---- reduce the 8 copies; emit norms and dense cnt_dst for the scan ----
__global__ __launch_bounds__(256) void rednorm_k(const unsigned* __restrict__ cs8,
                                                 const unsigned* __restrict__ cd8,
                                                 int* __restrict__ cnt_dst,
                                                 float* __restrict__ no,
                                                 float* __restrict__ ni) {
  int i = blockIdx.x * 256 + threadIdx.x;
  if (i >= NN) return;
  unsigned a = 0, b = 0;
#pragma unroll
  for (int x = 0; x < 8; ++x) {
    a += cs8[(size_t)x * NN + i];
    b += cd8[(size_t)x * NN + i];
  }
  cnt_dst[i] = (int)b;
  no[i] = rsqrtf((float)(a > 1u ? a : 1u));
  ni[i] = rsqrtf((float)(b > 1u ? b : 1u));
}

// ---- scan phase 1: per-1024-chunk exclusive scan + block sums ----
__global__ __launch_bounds__(256) void scan1_k(const int* __restrict__ cnt,
                                               int* __restrict__ excl, int* __restrict__ bsums) {
  __shared__ int lds[256];
  int t = threadIdx.x;
  int base = blockIdx.x * 1024 + t * 4;
  int v0 = (base + 0 < NN) ? cnt[base + 0] : 0;
  int v1 = (base + 1 < NN) ? cnt[base + 1] : 0;
  int v2 = (base + 2 < NN) ? cnt[base + 2] : 0;
  int v3 = (base + 3 < NN) ? cnt[base + 3] : 0;
  int s = v0 + v1 + v2 + v3;
  lds[t] = s;
  __syncthreads();
  int run = s;
  for (int off = 1; off < 256; off <<= 1) {
    int y = (t >= off) ? lds[t - off] : 0;
    __syncthreads();
    run += y;
    lds[t] = run;
    __syncthreads();
  }
  if (t == 255) bsums[blockIdx.x] = run;  // block total
  int ex = run - s;                       // exclusive prefix within block
  if (base + 0 < NN) excl[base + 0] = ex; ex += v0;
  if (base + 1 < NN) excl[base + 1] = ex; ex += v1;
  if (base + 2 < NN) excl[base + 2] = ex; ex += v2;
  if (base + 3 < NN) excl[base + 3] = ex;
}

// ---- scan phase 2: exclusive scan of the 98 block sums (single block) ----
__global__ __launch_bounds__(128) void scan2_k(int* __restrict__ bsums) {
  __shared__ int lds[128];
  int t = threadIdx.x;
  int s = (t < 98) ? bsums[t] : 0;
  lds[t] = s;
  __syncthreads();
  int run = s;
  for (int off = 1; off < 128; off <<= 1) {
    int y = (t >= off) ? lds[t - off] : 0;
    __syncthreads();
    run += y;
    lds[t] = run;
    __syncthreads();
  }
  if (t < 98) bsums[t] = run - s;  // exclusive
}

// ---- CSR fill: csr bucket of dst node gets src ids ----
__global__ __launch_bounds__(256) void fill_k(const int* __restrict__ src,
                                              const int* __restrict__ dst,
                                              const int* __restrict__ excl,
                                              const int* __restrict__ bsums,
                                              int* __restrict__ cursor, int* __restrict__ csr) {
  int i = blockIdx.x * 256 + threadIdx.x;
  if (i < EE) {
    int d = dst[i];
    int pos = atomicAdd(&cursor[d], 1);
    csr[excl[d] + bsums[d >> 10] + pos] = src[i];
  }
}

// ---- aggregation: half-wave (32 lanes x float4) per dst node, atomic-free ----
__global__ __launch_bounds__(256) void aggregate_k(const float* __restrict__ fin,
                                                   const float* __restrict__ nsrc,
                                                   const int* __restrict__ csr,
                                                   const int* __restrict__ excl,
                                                   const int* __restrict__ bsums,
                                                   float* __restrict__ outp) {
  int node = (blockIdx.x * 256 + threadIdx.x) >> 5;
  int lane = threadIdx.x & 31;
  if (node >= NN) return;
  int e0 = excl[node] + bsums[node >> 10];
  int e1 = (node == NN - 1) ? EE : (excl[node + 1] + bsums[(node + 1) >> 10]);
  float ax = 0.f, ay = 0.f, az = 0.f, aw = 0.f;
  int e = e0;
  for (; e + 2 <= e1; e += 2) {
    int s0 = csr[e];
    int s1 = csr[e + 1];
    float n0 = nsrc[s0];
    float n1 = nsrc[s1];
    float4 u = *reinterpret_cast<const float4*>(fin + s0 * DD + (lane << 2));
    float4 v = *reinterpret_cast<const float4*>(fin + s1 * DD + (lane << 2));
    ax += u.x * n0 + v.x * n1;
    ay += u.y * n0 + v.y * n1;
    az += u.z * n0 + v.z * n1;
    aw += u.w * n0 + v.w * n1;
  }
  if (e < e1) {
    int s0 = csr[e];
    float n0 = nsrc[s0];
    float4 u = *reinterpret_cast<const float4*>(fin + s0 * DD + (lane << 2));
    ax += u.x * n0;
    ay += u.y * n0;
    az += u.z * n0;
    aw += u.w * n0;
  }
  *reinterpret_cast<float4*>(outp + node * DD + (lane << 2)) = make_float4(ax, ay, az, aw);
}

// ---- fused GEMM + epilogue: out = act((agg @ W^T + b) * norm_in + resid) ----
__global__ __launch_bounds__(256) void gemm_k(const float* __restrict__ agg,
                                              const float* __restrict__ W,
                                              const float* __restrict__ bias,
                                              const float* __restrict__ nin,
                                              const float* __restrict__ resid,
                                              float* __restrict__ outp, int mode) {
  __shared__ float4 Wl[64 * 32];     // 64 rows of W, float4 over k (32KB)
  __shared__ float4 Rw[8][4][32];    // 8 half-waves x 4 rows x 128 floats (16KB)
  int t = threadIdx.x;
  int hw = t >> 5;
  int lane = t & 31;
  int rbase = blockIdx.x * 32 + hw * 4;

  for (int r = 0; r < 4; ++r) {
    Rw[hw][r][lane] = *reinterpret_cast<const float4*>(agg + (rbase + r) * DD + (lane << 2));
  }

  for (int p = 0; p < 2; ++p) {
    __syncthreads();
    const float4* Wg = reinterpret_cast<const float4*>(W) + p * (64 * 32);
    for (int i = t; i < 64 * 32; i += 256) Wl[i] = Wg[i];
    __syncthreads();

    float acc[4][2];
#pragma unroll
    for (int r = 0; r < 4; ++r) { acc[r][0] = 0.f; acc[r][1] = 0.f; }

#pragma unroll 4
    for (int tt = 0; tt < 32; ++tt) {
      int k4 = (tt + lane) & 31;
      float4 a0 = Rw[hw][0][k4];
      float4 a1 = Rw[hw][1][k4];
      float4 a2 = Rw[hw][2][k4];
      float4 a3 = Rw[hw][3][k4];
      float4 wA = Wl[(lane << 5) + k4];
      float4 wB = Wl[((lane + 32) << 5) + k4];
      acc[0][0] += dot4(a0, wA); acc[0][1] += dot4(a0, wB);
      acc[1][0] += dot4(a1, wA); acc[1][1] += dot4(a1, wB);
      acc[2][0] += dot4(a2, wA); acc[2][1] += dot4(a2, wB);
      acc[3][0] += dot4(a3, wA); acc[3][1] += dot4(a3, wB);
    }

    int jA = (p << 6) + lane;
    int jB = jA + 32;
    float bA = bias[jA];
    float bB = bias[jB];
#pragma unroll
    for (int r = 0; r < 4; ++r) {
      int node = rbase + r;
      float nv = nin[node];
      float oA = (acc[r][0] + bA) * nv;
      float oB = (acc[r][1] + bB) * nv;
      if (mode) {
        oA += resid[node * DD + jA];
        oB += resid[node * DD + jB];
        oA = fmaxf(oA, 0.f);
        oB = fmaxf(oB, 0.f);
      }
      outp[node * DD + jA] = oA;
      outp[node * DD + jB] = oB;
    }
  }
}

extern "C" void kernel_launch(void* const* d_in, const int* in_sizes, int n_in,
                              void* d_out, int out_size, void* d_ws, size_t ws_size,
                              hipStream_t stream) {
  const float* feat = (const float*)d_in[0];
  const int* src = (const int*)d_in[1];
  const int* dst = (const int*)d_in[2];
  const float* W1 = (const float*)d_in[3];
  const float* b1 = (const float*)d_in[4];
  const float* W2 = (const float*)d_in[5];
  const float* b2 = (const float*)d_in[6];
  const float* W3 = (const float*)d_in[7];
  const float* b3 = (const float*)d_in[8];
  float* out = (float*)d_out;

  // workspace layout
  int* cursor = (int*)d_ws;                 // N  (memset)
  int* cnt_dst = cursor + NN;               // N  (written densely by rednorm)
  int* excl = cnt_dst + NN;                 // N
  int* bsums = excl + NN;                   // 128
  float* norm_out = (float*)(bsums + 128);  // N
  float* norm_in = norm_out + NN;           // N
  int* csr = (int*)(norm_in + NN);          // E
  float* agg = (float*)(csr + EE);          // N*D
  // per-XCD histograms alias the agg buffer (dead until after rednorm)
  unsigned* cs8 = (unsigned*)agg;           // 8*N
  unsigned* cd8 = cs8 + 8 * NN;             // 8*N

  hipMemsetAsync(cursor, 0, (size_t)NN * sizeof(int), stream);
  hipMemsetAsync(cs8, 0, (size_t)16 * NN * sizeof(unsigned), stream);

  count8_k<<<(EE + 255) / 256, 256, 0, stream>>>(src, dst, cs8, cd8);
  rednorm_k<<<(NN + 255) / 256, 256, 0, stream>>>(cs8, cd8, cnt_dst, norm_out, norm_in);
  scan1_k<<<98, 256, 0, stream>>>(cnt_dst, excl, bsums);
  scan2_k<<<1, 128, 0, stream>>>(bsums);
  fill_k<<<(EE + 255) / 256, 256, 0, stream>>>(src, dst, excl, bsums, cursor, csr);

  // layer 1: feat -> agg ; gemm in-place on agg, residual=feat, relu
  aggregate_k<<<12500, 256, 0, stream>>>(feat, norm_out, csr, excl, bsums, agg);
  gemm_k<<<3125, 256, 0, stream>>>(agg, W1, b1, norm_in, feat, agg, 1);
  // layer 2: agg -> out ; gemm in-place on out, residual=agg, relu
  aggregate_k<<<12500, 256, 0, stream>>>(agg, norm_out, csr, excl, bsums, out);
  gemm_k<<<3125, 256, 0, stream>>>(out, W2, b2, norm_in, agg, out, 1);
  // layer 3: out -> agg ; gemm agg -> out, no residual, no act
  aggregate_k<<<12500, 256, 0, stream>>>(out, norm_out, csr, excl, bsums, agg);
  gemm_k<<<3125, 256, 0, stream>>>(agg, W3, b3, norm_in, nullptr, out, 0);
}

// Round 3
// 648.283 us; speedup vs baseline: 1.2558x; 1.2558x over previous
//
#include <hip/hip_runtime.h>

#define NN 100000
#define EE 1600000
#define DD 128
#define NB 512        // buckets = nodes >> 8
#define CAP 4608      // bucket capacity (mean 4096, +8 sigma)
#define CHUNK 8192    // edges per split block

static __device__ __forceinline__ float dot4(float4 a, float4 b) {
  return a.x * b.x + a.y * b.y + a.z * b.z + a.w * b.w;
}

// ---- init bucket cursors ----
__global__ __launch_bounds__(512) void initcur_k(int* __restrict__ cur_d,
                                                 int* __restrict__ cur_s) {
  int t = threadIdx.x;
  cur_d[t] = t * CAP;
  cur_s[t] = t * CAP;
}

// ---- pass 1: split edges into 512 buckets by high 9 bits (LDS hist + rank) ----
// tmp_d gets packed word (dst_low8 << 17 | src); tmp_s gets src_low8 byte.
__global__ __launch_bounds__(256) void split_k(const int* __restrict__ src,
                                               const int* __restrict__ dst,
                                               int* __restrict__ cur_d,
                                               int* __restrict__ cur_s,
                                               unsigned* __restrict__ tmp_d,
                                               unsigned char* __restrict__ tmp_s) {
  __shared__ int hd[NB], hs[NB], bd[NB], bs[NB];
  int t = threadIdx.x;
  int base = blockIdx.x * CHUNK;
  int end = base + CHUNK < EE ? base + CHUNK : EE;
  for (int b = t; b < NB; b += 256) { hd[b] = 0; hs[b] = 0; }
  __syncthreads();
  for (int i = base + t; i < end; i += 256) {
    atomicAdd(&hd[dst[i] >> 8], 1);
    atomicAdd(&hs[src[i] >> 8], 1);
  }
  __syncthreads();
  for (int b = t; b < NB; b += 256) {
    bd[b] = hd[b] ? atomicAdd(&cur_d[b], hd[b]) : 0;
    bs[b] = hs[b] ? atomicAdd(&cur_s[b], hs[b]) : 0;
    hd[b] = 0;  // reuse as rank counters
    hs[b] = 0;
  }
  __syncthreads();
  for (int i = base + t; i < end; i += 256) {
    int s = src[i];
    int d = dst[i];
    int bin = d >> 8;
    int r = atomicAdd(&hd[bin], 1);
    int pos = bd[bin] + r;
    if (pos < (bin + 1) * CAP) tmp_d[pos] = ((unsigned)(d & 255) << 17) | (unsigned)s;
    bin = s >> 8;
    r = atomicAdd(&hs[bin], 1);
    pos = bs[bin] + r;
    if (pos < (bin + 1) * CAP) tmp_s[pos] = (unsigned char)(s & 255);
  }
}

// ---- exclusive scan of 512 bucket counts -> dense CSR starts ----
__global__ __launch_bounds__(512) void scan512_k(const int* __restrict__ cur_d,
                                                 int* __restrict__ dstart) {
  __shared__ int lds[512];
  int t = threadIdx.x;
  int v = cur_d[t] - t * CAP;
  v = v < CAP ? v : CAP;
  lds[t] = v;
  __syncthreads();
  int run = v;
  for (int off = 1; off < 512; off <<= 1) {
    int y = (t >= off) ? lds[t - off] : 0;
    __syncthreads();
    run += y;
    lds[t] = run;
    __syncthreads();
  }
  dstart[t] = run - v;
}

// ---- pass 2 (dst): per-bucket LDS counting sort -> dense csr + rows + norm_in ----
__global__ __launch_bounds__(256) void bucket_dst_k(const unsigned* __restrict__ tmp_d,
                                                    const int* __restrict__ cur_d,
                                                    const int* __restrict__ dstart,
                                                    int* __restrict__ csr,
                                                    int* __restrict__ row_s,
                                                    int* __restrict__ row_e,
                                                    float* __restrict__ norm_in) {
  __shared__ unsigned stage[CAP];
  __shared__ int h[256], sc[256], rk[256];
  int b = blockIdx.x;
  int t = threadIdx.x;
  int cnt = cur_d[b] - b * CAP;
  cnt = cnt < CAP ? cnt : CAP;
  int ds = dstart[b];
  for (int i = t; i < cnt; i += 256) stage[i] = tmp_d[b * CAP + i];
  h[t] = 0;
  __syncthreads();
  for (int i = t; i < cnt; i += 256) atomicAdd(&h[stage[i] >> 17], 1);
  __syncthreads();
  int v = h[t];
  sc[t] = v;
  __syncthreads();
  int run = v;
  for (int off = 1; off < 256; off <<= 1) {
    int y = (t >= off) ? sc[t - off] : 0;
    __syncthreads();
    run += y;
    sc[t] = run;
    __syncthreads();
  }
  int excl = run - v;
  int n = b * 256 + t;
  if (n < NN) {
    row_s[n] = ds + excl;
    row_e[n] = ds + excl + v;
    norm_in[n] = rsqrtf((float)(v > 1 ? v : 1));
  }
  rk[t] = excl;
  __syncthreads();
  for (int i = t; i < cnt; i += 256) {
    unsigned w = stage[i];
    int r = atomicAdd(&rk[w >> 17], 1);
    csr[ds + r] = (int)(w & 0x1FFFFu);
  }
}

// ---- pass 2 (src): per-bucket byte histogram -> norm_out ----
__global__ __launch_bounds__(256) void bucket_src_k(const unsigned char* __restrict__ tmp_s,
                                                    const int* __restrict__ cur_s,
                                                    float* __restrict__ norm_out) {
  __shared__ int h[256];
  int b = blockIdx.x;
  int t = threadIdx.x;
  int cnt = cur_s[b] - b * CAP;
  cnt = cnt < CAP ? cnt : CAP;
  h[t] = 0;
  __syncthreads();
  const unsigned char* p = tmp_s + b * CAP;
  for (int i = t; i < cnt; i += 256) atomicAdd(&h[p[i]], 1);
  __syncthreads();
  int n = b * 256 + t;
  if (n < NN) norm_out[n] = rsqrtf((float)(h[t] > 1 ? h[t] : 1));
}

// ---- aggregation: half-wave (32 lanes x float4) per dst node, atomic-free ----
__global__ __launch_bounds__(256) void aggregate_k(const float* __restrict__ fin,
                                                   const float* __restrict__ nsrc,
                                                   const int* __restrict__ csr,
                                                   const int* __restrict__ row_s,
                                                   const int* __restrict__ row_e,
                                                   float* __restrict__ outp) {
  int node = (blockIdx.x * 256 + threadIdx.x) >> 5;
  int lane = threadIdx.x & 31;
  if (node >= NN) return;
  int e0 = row_s[node];
  int e1 = row_e[node];
  float ax = 0.f, ay = 0.f, az = 0.f, aw = 0.f;
  int e = e0;
  for (; e + 2 <= e1; e += 2) {
    int s0 = csr[e];
    int s1 = csr[e + 1];
    float n0 = nsrc[s0];
    float n1 = nsrc[s1];
    float4 u = *reinterpret_cast<const float4*>(fin + s0 * DD + (lane << 2));
    float4 v = *reinterpret_cast<const float4*>(fin + s1 * DD + (lane << 2));
    ax += u.x * n0 + v.x * n1;
    ay += u.y * n0 + v.y * n1;
    az += u.z * n0 + v.z * n1;
    aw += u.w * n0 + v.w * n1;
  }
  if (e < e1) {
    int s0 = csr[e];
    float n0 = nsrc[s0];
    float4 u = *reinterpret_cast<const float4*>(fin + s0 * DD + (lane << 2));
    ax += u.x * n0;
    ay += u.y * n0;
    az += u.z * n0;
    aw += u.w * n0;
  }
  *reinterpret_cast<float4*>(outp + node * DD + (lane << 2)) = make_float4(ax, ay, az, aw);
}

// ---- fused GEMM + epilogue: out = act((agg @ W^T + b) * norm_in + resid) ----
__global__ __launch_bounds__(256) void gemm_k(const float* __restrict__ agg,
                                              const float* __restrict__ W,
                                              const float* __restrict__ bias,
                                              const float* __restrict__ nin,
                                              const float* __restrict__ resid,
                                              float* __restrict__ outp, int mode) {
  __shared__ float4 Wl[64 * 32];     // 64 rows of W, float4 over k (32KB)
  __shared__ float4 Rw[8][4][32];    // 8 half-waves x 4 rows x 128 floats (16KB)
  int t = threadIdx.x;
  int hw = t >> 5;
  int lane = t & 31;
  int rbase = blockIdx.x * 32 + hw * 4;

  for (int r = 0; r < 4; ++r) {
    Rw[hw][r][lane] = *reinterpret_cast<const float4*>(agg + (rbase + r) * DD + (lane << 2));
  }

  for (int p = 0; p < 2; ++p) {
    __syncthreads();
    const float4* Wg = reinterpret_cast<const float4*>(W) + p * (64 * 32);
    for (int i = t; i < 64 * 32; i += 256) Wl[i] = Wg[i];
    __syncthreads();

    float acc[4][2];
#pragma unroll
    for (int r = 0; r < 4; ++r) { acc[r][0] = 0.f; acc[r][1] = 0.f; }

#pragma unroll 4
    for (int tt = 0; tt < 32; ++tt) {
      int k4 = (tt + lane) & 31;
      float4 a0 = Rw[hw][0][k4];
      float4 a1 = Rw[hw][1][k4];
      float4 a2 = Rw[hw][2][k4];
      float4 a3 = Rw[hw][3][k4];
      float4 wA = Wl[(lane << 5) + k4];
      float4 wB = Wl[((lane + 32) << 5) + k4];
      acc[0][0] += dot4(a0, wA); acc[0][1] += dot4(a0, wB);
      acc[1][0] += dot4(a1, wA); acc[1][1] += dot4(a1, wB);
      acc[2][0] += dot4(a2, wA); acc[2][1] += dot4(a2, wB);
      acc[3][0] += dot4(a3, wA); acc[3][1] += dot4(a3, wB);
    }

    int jA = (p << 6) + lane;
    int jB = jA + 32;
    float bA = bias[jA];
    float bB = bias[jB];
#pragma unroll
    for (int r = 0; r < 4; ++r) {
      int node = rbase + r;
      float nv = nin[node];
      float oA = (acc[r][0] + bA) * nv;
      float oB = (acc[r][1] + bB) * nv;
      if (mode) {
        oA += resid[node * DD + jA];
        oB += resid[node * DD + jB];
        oA = fmaxf(oA, 0.f);
        oB = fmaxf(oB, 0.f);
      }
      outp[node * DD + jA] = oA;
      outp[node * DD + jB] = oB;
    }
  }
}

extern "C" void kernel_launch(void* const* d_in, const int* in_sizes, int n_in,
                              void* d_out, int out_size, void* d_ws, size_t ws_size,
                              hipStream_t stream) {
  const float* feat = (const float*)d_in[0];
  const int* src = (const int*)d_in[1];
  const int* dst = (const int*)d_in[2];
  const float* W1 = (const float*)d_in[3];
  const float* b1 = (const float*)d_in[4];
  const float* W2 = (const float*)d_in[5];
  const float* b2 = (const float*)d_in[6];
  const float* W3 = (const float*)d_in[7];
  const float* b3 = (const float*)d_in[8];
  float* out = (float*)d_out;

  // workspace layout (ints): row_s, row_e, norms, cursors, dstart, csr, agg
  int* row_s = (int*)d_ws;                  // N
  int* row_e = row_s + NN;                  // N
  float* norm_out = (float*)(row_e + NN);   // N
  float* norm_in = norm_out + NN;           // N
  int* cur_d = (int*)(norm_in + NN);        // 512
  int* cur_s = cur_d + NB;                  // 512
  int* dstart = cur_s + NB;                 // 512
  int* csr = dstart + NB;                   // E  (offset 401536 ints, 16B aligned)
  float* agg = (float*)(csr + EE);          // N*D (offset 2001536 ints, 16B aligned)

  // bucket temporaries live in d_out (dead before layer-2 writes it)
  unsigned* tmp_d = (unsigned*)d_out;                    // 512*CAP words (9.4MB)
  unsigned char* tmp_s = (unsigned char*)d_out + (size_t)NB * CAP * 4;  // 2.4MB

  initcur_k<<<1, 512, 0, stream>>>(cur_d, cur_s);
  split_k<<<(EE + CHUNK - 1) / CHUNK, 256, 0, stream>>>(src, dst, cur_d, cur_s, tmp_d, tmp_s);
  scan512_k<<<1, 512, 0, stream>>>(cur_d, dstart);
  bucket_dst_k<<<NB, 256, 0, stream>>>(tmp_d, cur_d, dstart, csr, row_s, row_e, norm_in);
  bucket_src_k<<<NB, 256, 0, stream>>>(tmp_s, cur_s, norm_out);

  // layer 1: feat -> agg ; gemm in-place on agg, residual=feat, relu
  aggregate_k<<<12500, 256, 0, stream>>>(feat, norm_out, csr, row_s, row_e, agg);
  gemm_k<<<3125, 256, 0, stream>>>(agg, W1, b1, norm_in, feat, agg, 1);
  // layer 2: agg -> out ; gemm in-place on out, residual=agg, relu
  aggregate_k<<<12500, 256, 0, stream>>>(agg, norm_out, csr, row_s, row_e, out);
  gemm_k<<<3125, 256, 0, stream>>>(out, W2, b2, norm_in, agg, out, 1);
  // layer 3: out -> agg ; gemm agg -> out, no residual, no act
  aggregate_k<<<12500, 256, 0, stream>>>(out, norm_out, csr, row_s, row_e, agg);
  gemm_k<<<3125, 256, 0, stream>>>(agg, W3, b3, norm_in, nullptr, out, 0);
}

// Round 4
// 387.762 us; speedup vs baseline: 2.0995x; 1.6719x over previous
//
#include <hip/hip_runtime.h>

#define NN 100000
#define EE 1600000
#define DD 128
#define NB 512        // buckets = nodes >> 8
#define CAP 4608      // bucket capacity (mean 4096, +8 sigma)
#define CHUNK 8192    // edges per split block

typedef __attribute__((ext_vector_type(8))) short short8v;          // MFMA A/B frag (8 bf16)
typedef __attribute__((ext_vector_type(4))) float f32x4;            // MFMA C/D frag
typedef __attribute__((ext_vector_type(8))) unsigned short ushort8v;

static __device__ __forceinline__ unsigned short f2bf(float x) {    // round-to-nearest-even
  unsigned u = __builtin_bit_cast(unsigned, x);
  return (unsigned short)((u + 0x7FFFu + ((u >> 16) & 1u)) >> 16);
}
static __device__ __forceinline__ float bf2f(unsigned short u) {
  return __builtin_bit_cast(float, (unsigned)u << 16);
}

// ---- init bucket cursors ----
__global__ __launch_bounds__(512) void initcur_k(int* __restrict__ cur_d,
                                                 int* __restrict__ cur_s) {
  int t = threadIdx.x;
  cur_d[t] = t * CAP;
  cur_s[t] = t * CAP;
}

// ---- pass 1: split edges into 512 buckets by high 9 bits (LDS hist + rank) ----
__global__ __launch_bounds__(256) void split_k(const int* __restrict__ src,
                                               const int* __restrict__ dst,
                                               int* __restrict__ cur_d,
                                               int* __restrict__ cur_s,
                                               unsigned* __restrict__ tmp_d,
                                               unsigned char* __restrict__ tmp_s) {
  __shared__ int hd[NB], hs[NB], bd[NB], bs[NB];
  int t = threadIdx.x;
  int base = blockIdx.x * CHUNK;
  int end = base + CHUNK < EE ? base + CHUNK : EE;
  for (int b = t; b < NB; b += 256) { hd[b] = 0; hs[b] = 0; }
  __syncthreads();
  for (int i = base + t; i < end; i += 256) {
    atomicAdd(&hd[dst[i] >> 8], 1);
    atomicAdd(&hs[src[i] >> 8], 1);
  }
  __syncthreads();
  for (int b = t; b < NB; b += 256) {
    bd[b] = hd[b] ? atomicAdd(&cur_d[b], hd[b]) : 0;
    bs[b] = hs[b] ? atomicAdd(&cur_s[b], hs[b]) : 0;
    hd[b] = 0;  // reuse as rank counters
    hs[b] = 0;
  }
  __syncthreads();
  for (int i = base + t; i < end; i += 256) {
    int s = src[i];
    int d = dst[i];
    int bin = d >> 8;
    int r = atomicAdd(&hd[bin], 1);
    int pos = bd[bin] + r;
    if (pos < (bin + 1) * CAP) tmp_d[pos] = ((unsigned)(d & 255) << 17) | (unsigned)s;
    bin = s >> 8;
    r = atomicAdd(&hs[bin], 1);
    pos = bs[bin] + r;
    if (pos < (bin + 1) * CAP) tmp_s[pos] = (unsigned char)(s & 255);
  }
}

// ---- exclusive scan of 512 bucket counts -> dense CSR starts ----
__global__ __launch_bounds__(512) void scan512_k(const int* __restrict__ cur_d,
                                                 int* __restrict__ dstart) {
  __shared__ int lds[512];
  int t = threadIdx.x;
  int v = cur_d[t] - t * CAP;
  v = v < CAP ? v : CAP;
  lds[t] = v;
  __syncthreads();
  int run = v;
  for (int off = 1; off < 512; off <<= 1) {
    int y = (t >= off) ? lds[t - off] : 0;
    __syncthreads();
    run += y;
    lds[t] = run;
    __syncthreads();
  }
  dstart[t] = run - v;
}

// ---- pass 2 (dst): per-bucket LDS counting sort -> dense csr + rows + norm_in ----
__global__ __launch_bounds__(256) void bucket_dst_k(const unsigned* __restrict__ tmp_d,
                                                    const int* __restrict__ cur_d,
                                                    const int* __restrict__ dstart,
                                                    int* __restrict__ csr,
                                                    int* __restrict__ row_s,
                                                    int* __restrict__ row_e,
                                                    float* __restrict__ norm_in) {
  __shared__ unsigned stage[CAP];
  __shared__ int h[256], sc[256], rk[256];
  int b = blockIdx.x;
  int t = threadIdx.x;
  int cnt = cur_d[b] - b * CAP;
  cnt = cnt < CAP ? cnt : CAP;
  int ds = dstart[b];
  for (int i = t; i < cnt; i += 256) stage[i] = tmp_d[b * CAP + i];
  h[t] = 0;
  __syncthreads();
  for (int i = t; i < cnt; i += 256) atomicAdd(&h[stage[i] >> 17], 1);
  __syncthreads();
  int v = h[t];
  sc[t] = v;
  __syncthreads();
  int run = v;
  for (int off = 1; off < 256; off <<= 1) {
    int y = (t >= off) ? sc[t - off] : 0;
    __syncthreads();
    run += y;
    sc[t] = run;
    __syncthreads();
  }
  int excl = run - v;
  int n = b * 256 + t;
  if (n < NN) {
    row_s[n] = ds + excl;
    row_e[n] = ds + excl + v;
    norm_in[n] = rsqrtf((float)(v > 1 ? v : 1));
  }
  rk[t] = excl;
  __syncthreads();
  for (int i = t; i < cnt; i += 256) {
    unsigned w = stage[i];
    int r = atomicAdd(&rk[w >> 17], 1);
    csr[ds + r] = (int)(w & 0x1FFFFu);
  }
}

// ---- pass 2 (src): per-bucket byte histogram -> norm_out ----
__global__ __launch_bounds__(256) void bucket_src_k(const unsigned char* __restrict__ tmp_s,
                                                    const int* __restrict__ cur_s,
                                                    float* __restrict__ norm_out) {
  __shared__ int h[256];
  int b = blockIdx.x;
  int t = threadIdx.x;
  int cnt = cur_s[b] - b * CAP;
  cnt = cnt < CAP ? cnt : CAP;
  h[t] = 0;
  __syncthreads();
  const unsigned char* p = tmp_s + b * CAP;
  for (int i = t; i < cnt; i += 256) atomicAdd(&h[p[i]], 1);
  __syncthreads();
  int n = b * 256 + t;
  if (n < NN) norm_out[n] = rsqrtf((float)(h[t] > 1 ? h[t] : 1));
}

// ---- W fp32 -> bf16 (16384 elems, 16 blocks) ----
__global__ __launch_bounds__(256) void wconv_k(const float* __restrict__ w,
                                               unsigned short* __restrict__ o) {
  int i = blockIdx.x * 256 + threadIdx.x;
  float4 v = *reinterpret_cast<const float4*>(w + i * 4);
  unsigned short r0 = f2bf(v.x), r1 = f2bf(v.y), r2 = f2bf(v.z), r3 = f2bf(v.w);
  ushort4 pk = make_ushort4(r0, r1, r2, r3);
  *reinterpret_cast<ushort4*>(o + i * 4) = pk;
}

// ---- h1 = bf16(feat * norm_out) ----
__global__ __launch_bounds__(256) void hconv_k(const float* __restrict__ feat,
                                               const float* __restrict__ no,
                                               unsigned short* __restrict__ h) {
  int i = blockIdx.x * 256 + threadIdx.x;
  int node = i >> 4;
  int lane = i & 15;
  float n = no[node];
  const float* p = feat + node * DD + lane * 8;
  float4 a = *reinterpret_cast<const float4*>(p);
  float4 b = *reinterpret_cast<const float4*>(p + 4);
  ushort8v o;
  o[0] = f2bf(a.x * n); o[1] = f2bf(a.y * n); o[2] = f2bf(a.z * n); o[3] = f2bf(a.w * n);
  o[4] = f2bf(b.x * n); o[5] = f2bf(b.y * n); o[6] = f2bf(b.z * n); o[7] = f2bf(b.w * n);
  *reinterpret_cast<ushort8v*>(h + node * DD + lane * 8) = o;
}

// ---- aggregation: 16 lanes x bf16x8 per dst node; pure gather-sum (h pre-scaled) ----
__global__ __launch_bounds__(256) void aggregate_k(const unsigned short* __restrict__ h,
                                                   const int* __restrict__ csr,
                                                   const int* __restrict__ row_s,
                                                   const int* __restrict__ row_e,
                                                   unsigned short* __restrict__ aggout) {
  int node = (blockIdx.x * 256 + threadIdx.x) >> 4;
  int lane = threadIdx.x & 15;
  int e0 = row_s[node];
  int e1 = row_e[node];
  float acc[8] = {0.f, 0.f, 0.f, 0.f, 0.f, 0.f, 0.f, 0.f};
  int e = e0;
  for (; e + 2 <= e1; e += 2) {
    int s0 = csr[e];
    int s1 = csr[e + 1];
    ushort8v u = *reinterpret_cast<const ushort8v*>(h + (size_t)s0 * DD + lane * 8);
    ushort8v v = *reinterpret_cast<const ushort8v*>(h + (size_t)s1 * DD + lane * 8);
#pragma unroll
    for (int i = 0; i < 8; ++i) acc[i] += bf2f(u[i]) + bf2f(v[i]);
  }
  if (e < e1) {
    int s0 = csr[e];
    ushort8v u = *reinterpret_cast<const ushort8v*>(h + (size_t)s0 * DD + lane * 8);
#pragma unroll
    for (int i = 0; i < 8; ++i) acc[i] += bf2f(u[i]);
  }
  ushort8v o;
#pragma unroll
  for (int i = 0; i < 8; ++i) o[i] = f2bf(acc[i]);
  *reinterpret_cast<ushort8v*>(aggout + (size_t)node * DD + lane * 8) = o;
}

// ---- MFMA GEMM + epilogue; no LDS, no barriers ----
// out[m,j] = act((sum_k agg[m,k] W[j,k] + b[j]) * nin[m] + resid[m,j])
// hnext[m,j] = bf16(out[m,j] * nout[m])   (mode==1 only)
__global__ __launch_bounds__(256) void gemm_k(const unsigned short* __restrict__ A,
                                              const unsigned short* __restrict__ Wb,
                                              const float* __restrict__ bias,
                                              const float* __restrict__ nin,
                                              const float* __restrict__ nout,
                                              const float* __restrict__ resid,
                                              float* __restrict__ outp,
                                              unsigned short* __restrict__ hnext,
                                              int mode) {
  int wid = threadIdx.x >> 6;
  int lane = threadIdx.x & 63;
  int rbase = blockIdx.x * 64 + wid * 16;
  int l15 = lane & 15;
  int kgrp = lane >> 4;  // 0..3

  // A fragments: row = lane&15, k = kstep*32 + kgrp*8 + i  (16B contiguous)
  int arow = rbase + l15;
  int arow_c = arow < NN ? arow : NN - 1;
  const unsigned short* ap = A + (size_t)arow_c * DD + kgrp * 8;
  short8v af0 = *reinterpret_cast<const short8v*>(ap);
  short8v af1 = *reinterpret_cast<const short8v*>(ap + 32);
  short8v af2 = *reinterpret_cast<const short8v*>(ap + 64);
  short8v af3 = *reinterpret_cast<const short8v*>(ap + 96);

  // epilogue row constants: rows handled by this lane are kgrp*4+reg
  int nd0 = rbase + kgrp * 4;
  float nin4[4], nout4[4];
#pragma unroll
  for (int r = 0; r < 4; ++r) {
    int n = nd0 + r;
    int nc = n < NN ? n : NN - 1;
    nin4[r] = nin[nc];
    nout4[r] = (mode ? nout[nc] : 0.f);
  }

  for (int ct = 0; ct < 8; ++ct) {
    // B fragments: col = lane&15 (within tile), k = kstep*32 + kgrp*8 + i
    const unsigned short* wp = Wb + (size_t)(ct * 16 + l15) * DD + kgrp * 8;
    short8v b0 = *reinterpret_cast<const short8v*>(wp);
    short8v b1 = *reinterpret_cast<const short8v*>(wp + 32);
    short8v b2 = *reinterpret_cast<const short8v*>(wp + 64);
    short8v b3 = *reinterpret_cast<const short8v*>(wp + 96);
    f32x4 acc = {0.f, 0.f, 0.f, 0.f};
    acc = __builtin_amdgcn_mfma_f32_16x16x32_bf16(af0, b0, acc, 0, 0, 0);
    acc = __builtin_amdgcn_mfma_f32_16x16x32_bf16(af1, b1, acc, 0, 0, 0);
    acc = __builtin_amdgcn_mfma_f32_16x16x32_bf16(af2, b2, acc, 0, 0, 0);
    acc = __builtin_amdgcn_mfma_f32_16x16x32_bf16(af3, b3, acc, 0, 0, 0);

    int col = ct * 16 + l15;
    float bj = bias[col];
#pragma unroll
    for (int r = 0; r < 4; ++r) {
      int node = nd0 + r;
      if (node < NN) {
        float v = (acc[r] + bj) * nin4[r];
        size_t idx = (size_t)node * DD + col;
        if (mode) {
          v += resid[idx];
          v = fmaxf(v, 0.f);
          outp[idx] = v;
          hnext[idx] = f2bf(v * nout4[r]);
        } else {
          outp[idx] = v;
        }
      }
    }
  }
}

extern "C" void kernel_launch(void* const* d_in, const int* in_sizes, int n_in,
                              void* d_out, int out_size, void* d_ws, size_t ws_size,
                              hipStream_t stream) {
  const float* feat = (const float*)d_in[0];
  const int* src = (const int*)d_in[1];
  const int* dst = (const int*)d_in[2];
  const float* W1 = (const float*)d_in[3];
  const float* b1 = (const float*)d_in[4];
  const float* W2 = (const float*)d_in[5];
  const float* b2 = (const float*)d_in[6];
  const float* W3 = (const float*)d_in[7];
  const float* b3 = (const float*)d_in[8];
  float* out = (float*)d_out;

  // ws layout
  int* row_s = (int*)d_ws;                   // N
  int* row_e = row_s + NN;                   // N
  float* norm_out = (float*)(row_e + NN);    // N
  float* norm_in = norm_out + NN;            // N
  int* cur_d = (int*)(norm_in + NN);         // 512
  int* cur_s = cur_d + NB;                   // 512
  int* dstart = cur_s + NB;                  // 512
  int* pad = dstart + NB;                    // 512 (keep 16B alignment margin)
  unsigned short* Wbf = (unsigned short*)pad;      // 3*16384 bf16 (96KB)
  int* csr = (int*)(Wbf + 3 * 16384);              // E ints
  unsigned short* agg = (unsigned short*)(csr + EE);   // N*D bf16 (25.6MB)
  unsigned short* hbuf = agg + (size_t)NN * DD;        // N*D bf16 (25.6MB, last)

  // bucket temporaries live in d_out (dead before layer-1 gemm writes it)
  unsigned* tmp_d = (unsigned*)d_out;                                   // 9.4MB
  unsigned char* tmp_s = (unsigned char*)d_out + (size_t)NB * CAP * 4;  // 2.4MB

  initcur_k<<<1, 512, 0, stream>>>(cur_d, cur_s);
  split_k<<<(EE + CHUNK - 1) / CHUNK, 256, 0, stream>>>(src, dst, cur_d, cur_s, tmp_d, tmp_s);
  scan512_k<<<1, 512, 0, stream>>>(cur_d, dstart);
  bucket_dst_k<<<NB, 256, 0, stream>>>(tmp_d, cur_d, dstart, csr, row_s, row_e, norm_in);
  bucket_src_k<<<NB, 256, 0, stream>>>(tmp_s, cur_s, norm_out);

  wconv_k<<<16, 256, 0, stream>>>(W1, Wbf);
  wconv_k<<<16, 256, 0, stream>>>(W2, Wbf + 16384);
  wconv_k<<<16, 256, 0, stream>>>(W3, Wbf + 32768);
  hconv_k<<<6250, 256, 0, stream>>>(feat, norm_out, hbuf);

  const int GG = (NN + 63) / 64;  // 1563
  // layer 1
  aggregate_k<<<6250, 256, 0, stream>>>(hbuf, csr, row_s, row_e, agg);
  gemm_k<<<GG, 256, 0, stream>>>(agg, Wbf, b1, norm_in, norm_out, feat, out, hbuf, 1);
  // layer 2 (residual = out, in-place elementwise)
  aggregate_k<<<6250, 256, 0, stream>>>(hbuf, csr, row_s, row_e, agg);
  gemm_k<<<GG, 256, 0, stream>>>(agg, Wbf + 16384, b2, norm_in, norm_out, out, out, hbuf, 1);
  // layer 3 (no residual, no act, no h)
  aggregate_k<<<6250, 256, 0, stream>>>(hbuf, csr, row_s, row_e, agg);
  gemm_k<<<GG, 256, 0, stream>>>(agg, Wbf + 32768, b3, norm_in, norm_out, nullptr, out, nullptr, 0);
}